// Round 10
// baseline (160.048 us; speedup 1.0000x reference)
//
#include <hip/hip_runtime.h>
#include <hip/hip_bf16.h>
#include <stdint.h>

// Problem constants (fixed by the reference)
#define N_B   16384   // batch
#define D_DIM 1024    // input dim
#define K_K   512     // mixture components
#define L_DIM 128     // latent dim
#define H_DIM 64      // phi hidden
#define SX    1032    // x_bf LDS row stride in shorts (1024 + 8 pad)

typedef __attribute__((ext_vector_type(8))) short short8;   // 8 bf16 = 4 VGPRs (MFMA A/B frag)
typedef __attribute__((ext_vector_type(4))) float f32x4;    // MFMA C/D frag

__device__ __forceinline__ unsigned short f2bf(float f) {   // fp32 -> bf16 RNE (scalar)
    union { float f; unsigned int u; } c; c.f = f;
    unsigned int u = c.u;
    unsigned int r = (u + 0x7FFFu + ((u >> 16) & 1u)) >> 16;
    return (unsigned short)r;
}

__device__ __forceinline__ unsigned int pk2(float a, float b) {  // 2x fp32 -> packed bf16x2
    __hip_bfloat162 t = __float22bfloat162_rn(make_float2(a, b));
    union { __hip_bfloat162 h; unsigned int u; } c; c.h = t;
    return c.u;
}

// ---------------- kernel 1: prep ----------------
// 64 blocks x 256 threads. Per block: 8 components (h = relu(z@W1+b1) -> bf16,
// phi2[k] = ||h@W2+b2||^2 exact fp32), plus 1/64th of W2 -> bf16 conversion.
__global__ __launch_bounds__(256) void prep_kernel(
    const float* __restrict__ z, const float* __restrict__ W1,
    const float* __restrict__ b1, const float* __restrict__ W2,
    const float* __restrict__ b2, unsigned short* __restrict__ W2bf,
    unsigned short* __restrict__ h_bf, float* __restrict__ phi2) {
    __shared__ float zsh[8][L_DIM];     // 4 KB
    __shared__ float hsh[8][H_DIM];     // 2 KB
    __shared__ float redp[4][8];
    const int tid = threadIdx.x;
    const int k0 = blockIdx.x * 8;

    // --- W2 -> bf16: 64 blocks x 256 threads x 1 float4 = 16384 float4 = all of W2
    {
        int i = blockIdx.x * 256 + tid;
        float4 v = ((const float4*)W2)[i];
        uint2 o = make_uint2(pk2(v.x, v.y), pk2(v.z, v.w));
        *(uint2*)(W2bf + i * 4) = o;
    }
    // --- stage z rows for this block's 8 components
#pragma unroll
    for (int c = 0; c < 4; ++c) {
        int idx = c * 256 + tid;
        zsh[idx >> 7][idx & 127] = z[k0 * L_DIM + idx];
    }
    __syncthreads();
    // --- h = relu(z@W1+b1): thread t handles comps (t>>6) and (t>>6)+4 at col t&63
    {
        const int j = tid & 63, kk = tid >> 6;
        float bb = b1[j];
        float s0 = bb, s1 = bb;
        for (int l = 0; l < L_DIM; ++l) {
            float w = W1[l * H_DIM + j];
            s0 += zsh[kk][l] * w;
            s1 += zsh[kk + 4][l] * w;
        }
        float h0 = fmaxf(s0, 0.0f), h1 = fmaxf(s1, 0.0f);
        hsh[kk][j] = h0; hsh[kk + 4][j] = h1;
        h_bf[(k0 + kk) * H_DIM + j]     = f2bf(h0);
        h_bf[(k0 + kk + 4) * H_DIM + j] = f2bf(h1);
    }
    __syncthreads();
    // --- phi2[k] = ||h@W2 + b2||^2, exact fp32
    float ss[8] = {0.f, 0.f, 0.f, 0.f, 0.f, 0.f, 0.f, 0.f};
#pragma unroll
    for (int c = 0; c < 4; ++c) {
        int d = c * 256 + tid;
        float bb = b2[d];
        float a[8];
#pragma unroll
        for (int kk = 0; kk < 8; ++kk) a[kk] = bb;
        for (int j = 0; j < H_DIM; ++j) {
            float w = W2[j * D_DIM + d];
#pragma unroll
            for (int kk = 0; kk < 8; ++kk) a[kk] += hsh[kk][j] * w;
        }
#pragma unroll
        for (int kk = 0; kk < 8; ++kk) ss[kk] += a[kk] * a[kk];
    }
    const int lane = tid & 63, wv = tid >> 6;
#pragma unroll
    for (int kk = 0; kk < 8; ++kk) {
        float v = ss[kk];
#pragma unroll
        for (int o = 1; o < 64; o <<= 1) v += __shfl_xor(v, o, 64);
        if (lane == 0) redp[wv][kk] = v;
    }
    __syncthreads();
    if (tid < 8) phi2[k0 + tid] = redp[0][tid] + redp[1][tid] + redp[2][tid] + redp[3][tid];
}

// ---------------- kernel 2: u_kernel -- the x streamer ----------------
// 1024 blocks x 256 threads, 33 KB LDS, slim VGPR -> 3-4 blocks/CU. Per block:
// stage one 16-row x tile (strictly linear float4 loads, 2 batches x 8
// independent), exact fp32 xn = x^2 - 2*x.b2 per row, then stage 1 only:
// u[0:16, wv*16:+16] = x @ W2^T (LDS A-frags, W2 ring-8). Writes u fp32 + xn
// to ws. No stage-2 baggage -> short blocks; cross-BLOCK overlap keeps the
// HBM stream continuous (in-block pipelining kept failing, R4/R8/R9).
__global__ __launch_bounds__(256) void u_kernel(
    const float* __restrict__ x, const unsigned short* __restrict__ W2bf,
    const float* __restrict__ b2, float* __restrict__ u_out,
    float* __restrict__ xn_out) {
    __shared__ __align__(16) unsigned short x_bf[16 * SX];      // 33 KB bf16 x tile

    const int tid = threadIdx.x;
    const int wv  = tid >> 6;      // wave 0..3
    const int l   = tid & 63;      // lane
    const int lm  = l & 15;
    const int q   = l >> 4;        // quad 0..3
    const int n0  = blockIdx.x * 16;

    // b2 slices: lane l covers cols sub*256 + l*4 (coalesced)
    float4 b2r[4];
#pragma unroll
    for (int sub = 0; sub < 4; ++sub)
        b2r[sub] = ((const float4*)b2)[sub * 64 + l];

    // ---- stage rows [wv*4, wv*4+4): 2 batches x 8 independent linear loads ----
    float x2a[4], xba[4];
#pragma unroll
    for (int batch = 0; batch < 2; ++batch) {
        const int r0 = wv * 4 + batch * 2;
        float4 xv[8];
#pragma unroll
        for (int s = 0; s < 2; ++s)
#pragma unroll
            for (int sub = 0; sub < 4; ++sub)
                xv[s * 4 + sub] = *(const float4*)(x + (size_t)(n0 + r0 + s) * D_DIM + sub * 256 + l * 4);
#pragma unroll
        for (int s = 0; s < 2; ++s) {
            float s2 = 0.f, sb = 0.f;
#pragma unroll
            for (int sub = 0; sub < 4; ++sub) {
                float4 v = xv[s * 4 + sub];
                s2 += v.x*v.x + v.y*v.y + v.z*v.z + v.w*v.w;
                sb += v.x*b2r[sub].x + v.y*b2r[sub].y + v.z*b2r[sub].z + v.w*b2r[sub].w;
                uint2 o = make_uint2(pk2(v.x, v.y), pk2(v.z, v.w));
                *(uint2*)&x_bf[(r0 + s) * SX + sub * 256 + l * 4] = o;
            }
            x2a[batch * 2 + s] = s2; xba[batch * 2 + s] = sb;
        }
    }
    // per-row reduce; xn = x2 - 2*xb2 straight to global (rows wave-private)
#pragma unroll
    for (int s = 0; s < 4; ++s) {
        float a = x2a[s], b = xba[s];
#pragma unroll
        for (int o = 1; o < 64; o <<= 1) { a += __shfl_xor(a, o, 64); b += __shfl_xor(b, o, 64); }
        if (l == 0) xn_out[n0 + wv * 4 + s] = a - 2.f * b;
    }
    __syncthreads();

    // ---- stage 1: u[0:16, wv*16:+16] = x @ W2^T over K=1024, W2 ring-8 ----
    const unsigned short* w2row = W2bf + (size_t)(wv * 16 + lm) * D_DIM + q * 8;
    short8 wf[8];
#pragma unroll
    for (int p = 0; p < 8; ++p)
        wf[p] = *(const short8*)(w2row + p * 32);
    f32x4 c1 = {};
#pragma unroll
    for (int ks = 0; ks < 32; ++ks) {
        short8 bw = wf[ks & 7];
        if (ks < 24)
            wf[ks & 7] = *(const short8*)(w2row + (ks + 8) * 32);
        short8 a0 = *(const short8*)&x_bf[lm * SX + ks * 32 + q * 8];
        c1 = __builtin_amdgcn_mfma_f32_16x16x32_bf16(a0, bw, c1, 0, 0, 0);
    }
    // store u fp32 (C layout: row = q*4 + r, col = wv*16 + lm)
#pragma unroll
    for (int r = 0; r < 4; ++r)
        u_out[(size_t)(n0 + q * 4 + r) * H_DIM + wv * 16 + lm] = c1[r];
}

// ---------------- kernel 3: s_kernel -- stage 2 + epilogue ----------------
// 512 blocks x 256 threads, ~3 KB LDS. All inputs L2/L3-hot (u 4 MB, h 64 KB).
// S = h @ u^T (512x32), sq = phi2[m] + xn[n] - 2S, sum_k exp(-sq), log, mean.
__global__ __launch_bounds__(256) void s_kernel(
    const float* __restrict__ u, const float* __restrict__ xn_g,
    const unsigned short* __restrict__ h_bf, const float* __restrict__ phi2,
    float* __restrict__ out) {
    __shared__ float phi2s[K_K];        // 2 KB
    __shared__ float red[4][32];        // 512 B

    const int tid = threadIdx.x;
    const int wv  = tid >> 6;      // wave 0..3
    const int l   = tid & 63;      // lane
    const int lm  = l & 15;
    const int q   = l >> 4;        // quad 0..3
    const int n0  = blockIdx.x * 32;

    phi2s[tid]       = phi2[tid];
    phi2s[256 + tid] = phi2[256 + tid];

    // u B-frags from global fp32, packed to bf16 in-register
    short8 bfr[2][2];   // [ks][j]
#pragma unroll
    for (int ks = 0; ks < 2; ++ks)
#pragma unroll
        for (int j = 0; j < 2; ++j) {
            const float* up = u + (size_t)(n0 + j * 16 + lm) * H_DIM + ks * 32 + q * 8;
            float4 p0 = *(const float4*)up;
            float4 p1 = *(const float4*)(up + 4);
            union { short8 s8; unsigned int uu[4]; } pb;
            pb.uu[0] = pk2(p0.x, p0.y);
            pb.uu[1] = pk2(p0.z, p0.w);
            pb.uu[2] = pk2(p1.x, p1.y);
            pb.uu[3] = pk2(p1.z, p1.w);
            bfr[ks][j] = pb.s8;
        }
    __syncthreads();   // phi2s ready

    // S = h @ u^T: wave wv covers component rows [wv*128, wv*128+128)
    f32x4 acc[8][2] = {};
#pragma unroll
    for (int ks = 0; ks < 2; ++ks) {
        const int ko = ks * 32 + q * 8;
#pragma unroll
        for (int i = 0; i < 8; ++i) {
            short8 a = *(const short8*)(h_bf + (size_t)(wv * 128 + i * 16 + lm) * H_DIM + ko);
#pragma unroll
            for (int j = 0; j < 2; ++j)
                acc[i][j] = __builtin_amdgcn_mfma_f32_16x16x32_bf16(a, bfr[ks][j], acc[i][j], 0, 0, 0);
        }
    }
    // epilogue: sq = phi2[m] + xn[n] - 2*S; sum_k exp(-sq)
    float xn0 = xn_g[n0 + lm];
    float xn1 = xn_g[n0 + 16 + lm];
    float cs0 = 0.f, cs1 = 0.f;
#pragma unroll
    for (int i = 0; i < 8; ++i) {
#pragma unroll
        for (int r = 0; r < 4; ++r) {
            float p2 = phi2s[wv * 128 + i * 16 + q * 4 + r];
            cs0 += __expf(-(p2 + xn0 - 2.f * acc[i][0][r]));
            cs1 += __expf(-(p2 + xn1 - 2.f * acc[i][1][r]));
        }
    }
    cs0 += __shfl_xor(cs0, 16, 64); cs0 += __shfl_xor(cs0, 32, 64);
    cs1 += __shfl_xor(cs1, 16, 64); cs1 += __shfl_xor(cs1, 32, 64);
    if (l < 16) { red[wv][l] = cs0; red[wv][16 + l] = cs1; }
    __syncthreads();
    // fused final reduction: mean over this block's 32 rows of log(mean_k lik + eps)
    if (tid < 32) {
        float row_lik = red[0][tid] + red[1][tid] + red[2][tid] + red[3][tid];
        float lg = __logf(row_lik * (1.0f / (float)K_K) + 1e-9f);
        lg += __shfl_xor(lg, 1, 64);
        lg += __shfl_xor(lg, 2, 64);
        lg += __shfl_xor(lg, 4, 64);
        lg += __shfl_xor(lg, 8, 64);
        lg += __shfl_xor(lg, 16, 64);
        if (tid == 0) atomicAdd(out, lg * (1.0f / (float)N_B));
    }
}

extern "C" void kernel_launch(void* const* d_in, const int* in_sizes, int n_in,
                              void* d_out, int out_size, void* d_ws, size_t ws_size,
                              hipStream_t stream) {
    const float* x  = (const float*)d_in[0];
    const float* z  = (const float*)d_in[1];
    const float* W1 = (const float*)d_in[2];
    const float* b1 = (const float*)d_in[3];
    const float* W2 = (const float*)d_in[4];
    const float* b2 = (const float*)d_in[5];

    char* ws = (char*)d_ws;
    unsigned short* W2bf = (unsigned short*)(ws);               // 128 KB
    unsigned short* h_bf = (unsigned short*)(ws + 131072);      // 64 KB
    float*          phi2 = (float*)(ws + 196608);               // 2 KB
    float*          u    = (float*)(ws + 200704);               // 4 MB (16384x64 fp32)
    float*          xn   = (float*)(ws + 200704 + 4194304);     // 64 KB

    hipMemsetAsync(d_out, 0, sizeof(float), stream);
    prep_kernel<<<64, 256, 0, stream>>>(z, W1, b1, W2, b2, W2bf, h_bf, phi2);
    u_kernel<<<N_B / 16, 256, 0, stream>>>(x, W2bf, b2, u, xn);
    s_kernel<<<N_B / 32, 256, 0, stream>>>(u, xn, h_bf, phi2, (float*)d_out);
}

// Round 11
// 152.203 us; speedup vs baseline: 1.0515x; 1.0515x over previous
//
#include <hip/hip_runtime.h>
#include <hip/hip_bf16.h>
#include <stdint.h>

// Problem constants (fixed by the reference)
#define N_B   16384   // batch
#define D_DIM 1024    // input dim
#define K_K   512     // mixture components
#define L_DIM 128     // latent dim
#define H_DIM 64      // phi hidden
#define SX    1032    // x_bf LDS row stride in shorts (2064 B; DMA writes 2048 B, 16 B pad)

typedef __attribute__((ext_vector_type(8))) short short8;   // 8 bf16 = 4 VGPRs (MFMA A/B frag)
typedef __attribute__((ext_vector_type(4))) float f32x4;    // MFMA C/D frag
typedef unsigned int u32;

__device__ __forceinline__ unsigned short f2bf(float f) {   // fp32 -> bf16 RNE (scalar)
    union { float f; unsigned int u; } c; c.f = f;
    unsigned int u = c.u;
    unsigned int r = (u + 0x7FFFu + ((u >> 16) & 1u)) >> 16;
    return (unsigned short)r;
}

__device__ __forceinline__ unsigned int pk2(float a, float b) {  // 2x fp32 -> packed bf16x2
    __hip_bfloat162 t = __float22bfloat162_rn(make_float2(a, b));
    union { __hip_bfloat162 h; unsigned int u; } c; c.h = t;
    return c.u;
}

// async 16-B global -> LDS DMA (no destination VGPRs; lane i lands at l + i*16)
__device__ __forceinline__ void dma16(const void* g, void* l) {
    __builtin_amdgcn_global_load_lds(
        (const __attribute__((address_space(1))) u32*)g,
        (__attribute__((address_space(3))) u32*)l, 16, 0, 0);
}

// ---------------- kernel 1: prep (merged with x-stream convert) ----------------
// 4096 blocks x 256 threads. Every block: 4 rows of x (wave = one row, strictly
// coalesced) -> bf16 x_bf + EXACT fp32 x2[row], xb2[row] (pure streaming pass,
// structurally identical to the 6.5 TB/s fills). Blocks 0..63 additionally do
// the old prep: W2 -> bf16, h = relu(z@W1+b1) -> bf16, phi2 = ||h@W2+b2||^2.
__global__ __launch_bounds__(256) void prep_kernel(
    const float* __restrict__ x, const float* __restrict__ z,
    const float* __restrict__ W1, const float* __restrict__ b1,
    const float* __restrict__ W2, const float* __restrict__ b2,
    unsigned short* __restrict__ W2bf, unsigned short* __restrict__ h_bf,
    float* __restrict__ phi2, unsigned short* __restrict__ xbf,
    float* __restrict__ x2g, float* __restrict__ xb2g) {
    const int tid = threadIdx.x;
    const int wv  = tid >> 6;
    const int l   = tid & 63;

    // ---- x stream: wave wv owns row blockIdx*4 + wv (1024 floats) ----
    {
        const int row = blockIdx.x * 4 + wv;
        const float4* xr = (const float4*)(x + (size_t)row * D_DIM);
        uint2* xo = (uint2*)(xbf + (size_t)row * D_DIM);
        float s2 = 0.f, sb = 0.f;
#pragma unroll
        for (int s = 0; s < 4; ++s) {
            float4 v = xr[s * 64 + l];                    // coalesced
            float4 bb = ((const float4*)b2)[s * 64 + l];  // L2-hot
            s2 += v.x*v.x + v.y*v.y + v.z*v.z + v.w*v.w;
            sb += v.x*bb.x + v.y*bb.y + v.z*bb.z + v.w*bb.w;
            xo[s * 64 + l] = make_uint2(pk2(v.x, v.y), pk2(v.z, v.w));
        }
#pragma unroll
        for (int o = 1; o < 64; o <<= 1) { s2 += __shfl_xor(s2, o, 64); sb += __shfl_xor(sb, o, 64); }
        if (l == 0) { x2g[row] = s2; xb2g[row] = sb; }
    }

    if (blockIdx.x >= 64) return;

    // ---- classic prep on blocks 0..63 (8 components each + W2 convert) ----
    __shared__ float zsh[8][L_DIM];
    __shared__ float hsh[8][H_DIM];
    __shared__ float redp[4][8];
    const int k0 = blockIdx.x * 8;
    {
        int i = blockIdx.x * 256 + tid;     // 64 blocks x 256 x float4 = all of W2
        float4 v = ((const float4*)W2)[i];
        *(uint2*)(W2bf + i * 4) = make_uint2(pk2(v.x, v.y), pk2(v.z, v.w));
    }
#pragma unroll
    for (int c = 0; c < 4; ++c) {
        int idx = c * 256 + tid;
        zsh[idx >> 7][idx & 127] = z[k0 * L_DIM + idx];
    }
    __syncthreads();
    {
        const int j = tid & 63, kk = tid >> 6;
        float bb = b1[j];
        float s0 = bb, s1 = bb;
        for (int ll = 0; ll < L_DIM; ++ll) {
            float w = W1[ll * H_DIM + j];
            s0 += zsh[kk][ll] * w;
            s1 += zsh[kk + 4][ll] * w;
        }
        float h0 = fmaxf(s0, 0.0f), h1 = fmaxf(s1, 0.0f);
        hsh[kk][j] = h0; hsh[kk + 4][j] = h1;
        h_bf[(k0 + kk) * H_DIM + j]     = f2bf(h0);
        h_bf[(k0 + kk + 4) * H_DIM + j] = f2bf(h1);
    }
    __syncthreads();
    float ss[8] = {0.f, 0.f, 0.f, 0.f, 0.f, 0.f, 0.f, 0.f};
#pragma unroll
    for (int c = 0; c < 4; ++c) {
        int d = c * 256 + tid;
        float bb = b2[d];
        float a[8];
#pragma unroll
        for (int kk = 0; kk < 8; ++kk) a[kk] = bb;
        for (int j = 0; j < H_DIM; ++j) {
            float w = W2[j * D_DIM + d];
#pragma unroll
            for (int kk = 0; kk < 8; ++kk) a[kk] += hsh[kk][j] * w;
        }
#pragma unroll
        for (int kk = 0; kk < 8; ++kk) ss[kk] += a[kk] * a[kk];
    }
#pragma unroll
    for (int kk = 0; kk < 8; ++kk) {
        float v = ss[kk];
#pragma unroll
        for (int o = 1; o < 64; o <<= 1) v += __shfl_xor(v, o, 64);
        if (l == 0) redp[wv][kk] = v;
    }
    __syncthreads();
    if (tid < 8) phi2[k0 + tid] = redp[0][tid] + redp[1][tid] + redp[2][tid] + redp[3][tid];
}

// ---------------- main kernel: per block = one 32-row batch tile ----------------
// 512 blocks x 256 threads, ~74 KB LDS -> 2 blocks/CU. Staging: 16 async
// global_load_lds DMAs per wave (bf16 x_bf, L3-resident after prep; ZERO dest
// VGPRs, zero consume phase), one barrier. Stage 1: u[:, wv*16:+16] = x @ W2^T
// (LDS A-frags, W2 ring-8). Stage 2: S = h @ u^T + fused exp/log/mean epilogue
// (xn read precomputed from prep).
__global__ __launch_bounds__(256) void main_kernel(
    const unsigned short* __restrict__ xbf, const unsigned short* __restrict__ W2bf,
    const unsigned short* __restrict__ h_bf, const float* __restrict__ phi2,
    const float* __restrict__ x2g, const float* __restrict__ xb2g,
    float* __restrict__ out) {
    __shared__ __align__(16) unsigned short x_bf[32 * SX];      // 66 KB bf16 x tile
    __shared__ __align__(16) unsigned short u_tile[32 * 72];    // 4.5 KB, stride 72
    __shared__ float phi2s[K_K];                                // 2 KB
    __shared__ float red[4][32];                                // 512 B

    const int tid = threadIdx.x;
    const int wv  = tid >> 6;      // wave 0..3
    const int l   = tid & 63;      // lane
    const int lm  = l & 15;
    const int q   = l >> 4;        // quad 0..3
    const int n0  = blockIdx.x * 32;

    // ---- async DMA staging: wave wv stages rows [wv*8, wv*8+8), 2x1KB per row ----
    const char* xsrc = (const char*)xbf + (size_t)(n0 + wv * 8) * 2048 + (size_t)l * 16;
#pragma unroll
    for (int r = 0; r < 8; ++r)
#pragma unroll
        for (int c = 0; c < 2; ++c)
            dma16(xsrc + r * 2048 + c * 1024, &x_bf[(wv * 8 + r) * SX + c * 512]);
    // phi2 stage while DMAs fly (drained together by the barrier)
    phi2s[tid]       = phi2[tid];
    phi2s[256 + tid] = phi2[256 + tid];
    __syncthreads();

    // ---- stage 1: u[:, wv*16:+16] = x @ W2^T over full K=1024, W2 ring-8 ----
    const unsigned short* w2row = W2bf + (size_t)(wv * 16 + lm) * D_DIM + q * 8;
    short8 wf[8];
#pragma unroll
    for (int p = 0; p < 8; ++p)
        wf[p] = *(const short8*)(w2row + p * 32);
    f32x4 c1[2] = {};
#pragma unroll
    for (int ks = 0; ks < 32; ++ks) {
        const int k0 = ks * 32 + q * 8;
        short8 bw = wf[ks & 7];
        if (ks < 24)
            wf[ks & 7] = *(const short8*)(w2row + (ks + 8) * 32);
        short8 a0 = *(const short8*)&x_bf[lm * SX + k0];          // x rows 0..15
        short8 a1 = *(const short8*)&x_bf[(16 + lm) * SX + k0];   // x rows 16..31
        c1[0] = __builtin_amdgcn_mfma_f32_16x16x32_bf16(a0, bw, c1[0], 0, 0, 0);
        c1[1] = __builtin_amdgcn_mfma_f32_16x16x32_bf16(a1, bw, c1[1], 0, 0, 0);
    }
    // write this wave's 16 u columns (C layout: row = i*16 + q*4 + r, col = wv*16+lm)
#pragma unroll
    for (int i = 0; i < 2; ++i)
#pragma unroll
        for (int r = 0; r < 4; ++r)
            u_tile[(i * 16 + q * 4 + r) * 72 + wv * 16 + lm] = f2bf(c1[i][r]);
    __syncthreads();

    // ---- stage 2: S = h @ u^T, wave wv covers component rows [wv*128, wv*128+128) ----
    f32x4 acc[8][2] = {};
#pragma unroll
    for (int ks = 0; ks < 2; ++ks) {
        const int ko = ks * 32 + q * 8;
        short8 bfr[2];
#pragma unroll
        for (int j = 0; j < 2; ++j)
            bfr[j] = *(const short8*)&u_tile[(j * 16 + lm) * 72 + ko];
#pragma unroll
        for (int i = 0; i < 8; ++i) {
            short8 a = *(const short8*)(h_bf + (size_t)(wv * 128 + i * 16 + lm) * H_DIM + ko);
#pragma unroll
            for (int j = 0; j < 2; ++j)
                acc[i][j] = __builtin_amdgcn_mfma_f32_16x16x32_bf16(a, bfr[j], acc[i][j], 0, 0, 0);
        }
    }
    // ---- epilogue: sq = phi2[m] + (x2[n] - 2*xb2[n]) - 2*S; sum_k exp(-sq) ----
    float xn0 = x2g[n0 + lm]      - 2.f * xb2g[n0 + lm];
    float xn1 = x2g[n0 + 16 + lm] - 2.f * xb2g[n0 + 16 + lm];
    float cs0 = 0.f, cs1 = 0.f;
#pragma unroll
    for (int i = 0; i < 8; ++i) {
#pragma unroll
        for (int r = 0; r < 4; ++r) {
            float p2 = phi2s[wv * 128 + i * 16 + q * 4 + r];
            cs0 += __expf(-(p2 + xn0 - 2.f * acc[i][0][r]));
            cs1 += __expf(-(p2 + xn1 - 2.f * acc[i][1][r]));
        }
    }
    cs0 += __shfl_xor(cs0, 16, 64); cs0 += __shfl_xor(cs0, 32, 64);
    cs1 += __shfl_xor(cs1, 16, 64); cs1 += __shfl_xor(cs1, 32, 64);
    if (l < 16) { red[wv][l] = cs0; red[wv][16 + l] = cs1; }
    __syncthreads();
    // ---- fused final reduction: mean over this block's 32 rows of log(mean_k lik + eps)
    if (tid < 32) {
        float row_lik = red[0][tid] + red[1][tid] + red[2][tid] + red[3][tid];
        float lg = __logf(row_lik * (1.0f / (float)K_K) + 1e-9f);
        lg += __shfl_xor(lg, 1, 64);
        lg += __shfl_xor(lg, 2, 64);
        lg += __shfl_xor(lg, 4, 64);
        lg += __shfl_xor(lg, 8, 64);
        lg += __shfl_xor(lg, 16, 64);
        if (tid == 0) atomicAdd(out, lg * (1.0f / (float)N_B));
    }
}

extern "C" void kernel_launch(void* const* d_in, const int* in_sizes, int n_in,
                              void* d_out, int out_size, void* d_ws, size_t ws_size,
                              hipStream_t stream) {
    const float* x  = (const float*)d_in[0];
    const float* z  = (const float*)d_in[1];
    const float* W1 = (const float*)d_in[2];
    const float* b1 = (const float*)d_in[3];
    const float* W2 = (const float*)d_in[4];
    const float* b2 = (const float*)d_in[5];

    char* ws = (char*)d_ws;
    unsigned short* W2bf = (unsigned short*)(ws);               // 128 KB
    unsigned short* h_bf = (unsigned short*)(ws + 131072);      // 64 KB
    float*          phi2 = (float*)(ws + 196608);               // 2 KB
    float*          x2g  = (float*)(ws + 200704);               // 64 KB
    float*          xb2g = (float*)(ws + 266240);               // 64 KB
    unsigned short* xbf  = (unsigned short*)(ws + 393216);      // 32 MB bf16 x

    hipMemsetAsync(d_out, 0, sizeof(float), stream);
    prep_kernel<<<N_B / 4, 256, 0, stream>>>(x, z, W1, b1, W2, b2,
                                             W2bf, h_bf, phi2, xbf, x2g, xb2g);
    main_kernel<<<N_B / 32, 256, 0, stream>>>(xbf, W2bf, h_bf, phi2, x2g, xb2g,
                                              (float*)d_out);
}